// Round 5
// baseline (141.202 us; speedup 1.0000x reference)
//
#include <hip/hip_runtime.h>
#include <stdint.h>

typedef unsigned long long u64;

// Problem constants (from reference file)
constexpr int B_ = 4;
constexpr int N_ = 160;
constexpr int T_ = 512;
constexpr int W_ = T_ / 64;   // 8 u64 words per 512-bit row
constexpr int LDP_ = N_ + 1;  // padded LDS plane stride (u64 units)

// ---------------------------------------------------------------------------
// Kernel 1: gather + bit-pack tag rows. grid = B*N blocks, 64 threads.
// Block 0 thread 0 also zeroes the done-counter for the fused finalize.
// ---------------------------------------------------------------------------
__global__ __launch_bounds__(64) void pack_tags(const float* __restrict__ emb,
                                                const int* __restrict__ preds,
                                                u64* __restrict__ tags,
                                                int* __restrict__ counter) {
    int row  = blockIdx.x;            // b*N + r
    int lane = threadIdx.x;           // 0..63
    if (row == 0 && lane == 0) *counter = 0;
    const float* src = emb + (long long)preds[row] * T_;
#pragma unroll
    for (int w = 0; w < W_; ++w) {
        float v = src[w * 64 + lane];
        u64 m = __ballot(v != 0.0f);
        if (lane == 0) tags[(long long)row * W_ + w] = m;
    }
}

// ---------------------------------------------------------------------------
// Kernel 2: pack_M + prefix-OR scan (P, cU, Mc) + AW table build.
// grid = B blocks, 256 threads.
// AW[b][k][i][w] = M & ~pre_i & ~OR(tags[i+1..k-1])   for i <= k
// built with thread=i, uniform k-loop (coalesced 64B stores per k-step).
// ---------------------------------------------------------------------------
__global__ __launch_bounds__(256) void pack_scan(const float* __restrict__ Mf,
                                                 const u64* __restrict__ tags,
                                                 u64* __restrict__ Mp,
                                                 float* __restrict__ cU,
                                                 float* __restrict__ Mc,
                                                 u64* __restrict__ AW) {
    __shared__ u64 S0[N_ * W_];
    __shared__ u64 S1[N_ * W_];
    __shared__ u64 Msh[W_];

    const int b    = blockIdx.x;
    const int tid  = threadIdx.x;
    const int lane = tid & 63;
    const int wv   = tid >> 6;        // wave id, 0..3

    for (int w = wv; w < W_; w += 4) {
        float v = Mf[(long long)b * T_ + w * 64 + lane];
        u64 m = __ballot(v != 0.0f);
        if (lane == 0) { Msh[w] = m; Mp[b * W_ + w] = m; }
    }
    for (int x = tid; x < N_ * W_; x += 256)
        S0[x] = tags[(long long)b * N_ * W_ + x];
    __syncthreads();

    // Hillis-Steele inclusive OR-scan along rows
    u64* src = S0;
    u64* dst = S1;
    for (int d = 1; d < N_; d <<= 1) {
        for (int x = tid; x < N_ * W_; x += 256) {
            int r = x >> 3;           // W_ == 8
            u64 v = src[x];
            if (r >= d) v |= src[x - d * W_];
            dst[x] = v;
        }
        __syncthreads();
        u64* t = src; src = dst; dst = t;
    }
    // src[r*W_+w] = P[r] = OR tags[0..r]

    if (tid < N_) {
        int c = 0;
#pragma unroll
        for (int w = 0; w < W_; ++w)
            c += __popcll(Msh[w] & ~src[tid * W_ + w]);
        cU[b * N_ + tid] = (float)c;
    }
    if (tid == 0) {
        int c = 0;
#pragma unroll
        for (int w = 0; w < W_; ++w) c += __popcll(Msh[w]);
        Mc[b] = (float)(c + 1);
    }

    // reload raw tags into the idle buffer (scan destroyed them)
    u64* tg = dst;
    for (int x = tid; x < N_ * W_; x += 256)
        tg[x] = tags[(long long)b * N_ * W_ + x];
    __syncthreads();

    // AW build: thread = i, uniform k loop, coalesced stores
    if (tid < N_) {
        const int i = tid;
        u64 aw[W_];
#pragma unroll
        for (int w = 0; w < W_; ++w) {
            u64 pre;
            if (i == 1) pre = 0ull;
            else {
                int sr = (i == 0) ? (N_ - 2) : (i - 2);
                pre = src[sr * W_ + w];
            }
            aw[w] = Msh[w] & ~pre;
        }
        for (int k = 0; k < N_; ++k) {
            if (k >= i) {
                u64* dstp = AW + (((long long)b * N_ + k) * N_ + i) * W_;
#pragma unroll
                for (int w = 0; w < W_; ++w) dstp[w] = aw[w];
                if (k > i) {
#pragma unroll
                    for (int w = 0; w < W_; ++w) aw[w] &= ~tg[k * W_ + w];
                }
            }
        }
    }
}

// ---------------------------------------------------------------------------
// Kernel 3: main + fused finalize. grid = (N, B) over k, 256 threads.
// No scans, 1 main barrier. Hybrid balanced sweep:
//   m >= 64 : thread = j, Bw register-cached, aw reads wave-uniform broadcast
//   m <  64 : flat pair-parallel sweep over (k+1)*m pairs (k large)
// ---------------------------------------------------------------------------
__global__ __launch_bounds__(256) void lambda_main(const u64* __restrict__ tags,
                                                   const u64* __restrict__ Mp,
                                                   const u64* __restrict__ AW,
                                                   const float* __restrict__ cU,
                                                   const float* __restrict__ Mc,
                                                   const float* __restrict__ scores,
                                                   double* __restrict__ partials,
                                                   int* __restrict__ counter,
                                                   float* __restrict__ out) {
    __shared__ u64 awL[W_ * LDP_];    // transposed [w][i]
    __shared__ u64 bLT[W_ * LDP_];    // transposed [w][j], rows k+1..N-1
    __shared__ float scoresL[N_];
    __shared__ float redF[4];
    __shared__ double redD[4];
    __shared__ int isLast;

    const int k   = blockIdx.x;
    const int b   = blockIdx.y;
    const int tid = threadIdx.x;
    const int m   = N_ - 1 - k;       // number of j values

    // M into registers (broadcast loads, no barrier needed)
    u64 Mr[W_];
#pragma unroll
    for (int w = 0; w < W_; ++w) Mr[w] = Mp[b * W_ + w];

    for (int x = tid; x < N_; x += 256) scoresL[x] = scores[b * N_ + x];

    // load aw rows 0..k (coalesced global) -> transposed LDS
    const u64* AWk = AW + ((long long)b * N_ + k) * N_ * W_;
    for (int x = tid; x < (k + 1) * W_; x += 256) {
        int r = x >> 3, w = x & 7;
        awL[w * LDP_ + r] = AWk[x];
    }
    // build b_j rows for j in (k, N) -> transposed LDS
    for (int x = tid; x < m * W_; x += 256) {
        int j = k + 1 + (x >> 3), w = x & 7;
        bLT[w * LDP_ + j] = Mr[w] & ~tags[((long long)b * N_ + j) * W_ + w];
    }
    __syncthreads();

    const float cUk = cU[b * N_ + k];
    float accLam = 0.0f, accC = 0.0f;

    if (m >= 64) {
        // thread = j path (Bw cached in registers, aw reads broadcast)
        if (tid < m) {
            const int j = k + 1 + tid;
            u64 Bw[W_];
#pragma unroll
            for (int w = 0; w < W_; ++w) Bw[w] = bLT[w * LDP_ + j];
            const float sj = scoresL[j];
            for (int i = 0; i <= k; ++i) {
                int cc = 0;
#pragma unroll
                for (int w = 0; w < W_; ++w)
                    cc += __popcll(awL[w * LDP_ + i] & Bw[w]);
                float lam = 1.0f / (1.0f + __expf(scoresL[i] - sj));
                accLam += lam;
                accC   += lam * (float)cc;
            }
        }
    } else if (m > 0) {
        // flat pair-parallel path (k+1 large here)
        const int npairs = (k + 1) * m;
        if (tid < npairs) {
            int cnt = (npairs - tid + 255) >> 8;
            int i   = tid / m;
            int jj  = tid - i * m;
            const int di = 256 / m;
            const int rj = 256 - di * m;
            for (int c = 0; c < cnt; ++c) {
                const int j = k + 1 + jj;
                int cc = 0;
#pragma unroll
                for (int w = 0; w < W_; ++w)
                    cc += __popcll(awL[w * LDP_ + i] & bLT[w * LDP_ + j]);
                float lam = 1.0f / (1.0f + __expf(scoresL[i] - scoresL[j]));
                accLam += lam;
                accC   += lam * (float)cc;
                i += di; jj += rj;
                if (jj >= m) { jj -= m; ++i; }
            }
        }
    }

    float val = cUk * accLam - accC;
    for (int off = 32; off >= 1; off >>= 1) val += __shfl_down(val, off, 64);
    if ((tid & 63) == 0) redF[tid >> 6] = val;
    __syncthreads();
    if (tid == 0) {
        float s = redF[0] + redF[1] + redF[2] + redF[3];
        float invlog = 1.0f / log2f((float)(k + 2));
        partials[b * N_ + k] = (double)(s * invlog) / (double)Mc[b];
        __threadfence();
        int done = atomicAdd(counter, 1);
        isLast = (done == N_ * B_ - 1) ? 1 : 0;
    }
    __syncthreads();

    if (isLast) {
        __threadfence();
        double s = 0.0;
        for (int x = tid; x < B_ * N_; x += 256) s += partials[x];
        for (int off = 32; off >= 1; off >>= 1) s += __shfl_down(s, off, 64);
        if ((tid & 63) == 0) redD[tid >> 6] = s;
        __syncthreads();
        if (tid == 0) {
            double t = redD[0] + redD[1] + redD[2] + redD[3];
            out[0] = (float)(t / ((double)(N_ + 1) * (double)B_));
        }
    }
}

// ---------------------------------------------------------------------------
extern "C" void kernel_launch(void* const* d_in, const int* in_sizes, int n_in,
                              void* d_out, int out_size, void* d_ws, size_t ws_size,
                              hipStream_t stream) {
    const float* y_scores = (const float*)d_in[0];   // B*N f32
    const float* Mf       = (const float*)d_in[1];   // B*T f32
    const float* emb      = (const float*)d_in[2];   // NUM_API*T f32
    const int*   preds    = (const int*)d_in[3];     // B*N i32
    float* out = (float*)d_out;

    // workspace layout (all 8-byte aligned)
    u64* tags = (u64*)d_ws;                               // B*N*W
    u64* Mp   = tags + (size_t)B_ * N_ * W_;              // B*W
    u64* AW   = Mp + (size_t)B_ * W_;                     // B*N*N*W (6.5 MB)
    double* partials = (double*)(AW + (size_t)B_ * N_ * N_ * W_);  // B*N
    float* cU = (float*)(partials + B_ * N_);             // B*N
    float* Mc = cU + B_ * N_;                             // B
    int* counter = (int*)(Mc + B_);                       // 1

    pack_tags<<<B_ * N_, 64, 0, stream>>>(emb, preds, tags, counter);
    pack_scan<<<B_, 256, 0, stream>>>(Mf, tags, Mp, cU, Mc, AW);
    dim3 grid(N_, B_);
    lambda_main<<<grid, 256, 0, stream>>>(tags, Mp, AW, cU, Mc, y_scores,
                                          partials, counter, out);
}

// Round 6
// 122.696 us; speedup vs baseline: 1.1508x; 1.1508x over previous
//
#include <hip/hip_runtime.h>
#include <stdint.h>

typedef unsigned long long u64;

// Problem constants (from reference file)
constexpr int B_ = 4;
constexpr int N_ = 160;
constexpr int T_ = 512;
constexpr int W_ = T_ / 64;     // 8 u64 words per 512-bit row
constexpr int LDP_ = N_ + 1;    // padded LDS plane stride (u64 units)
constexpr int KC_ = 4;          // k values per block
constexpr int NBLK_ = N_ / KC_; // 40 k-chunks

// ---------------------------------------------------------------------------
// Kernel 1: gather + bit-pack tag rows. grid = B*N blocks, 64 threads.
// Block 0 thread 0 zeroes the done-counter for the fused finalize.
// ---------------------------------------------------------------------------
__global__ __launch_bounds__(64) void pack_tags(const float* __restrict__ emb,
                                                const int* __restrict__ preds,
                                                u64* __restrict__ tags,
                                                int* __restrict__ counter) {
    int row  = blockIdx.x;            // b*N + r
    int lane = threadIdx.x;           // 0..63
    if (row == 0 && lane == 0) *counter = 0;
    const float* src = emb + (long long)preds[row] * T_;
#pragma unroll
    for (int w = 0; w < W_; ++w) {
        float v = src[w * 64 + lane];
        u64 m = __ballot(v != 0.0f);
        if (lane == 0) tags[(long long)row * W_ + w] = m;
    }
}

// ---------------------------------------------------------------------------
// Kernel 2: everything else. grid = (NBLK_, B_), 256 threads.
// Block (kc,b) handles k in [4kc, 4kc+4):
//   - one global pass loads tags -> T plane, prefix-scan init, BT[j]=M&~tag[j]
//   - 8-step prefix OR-scan  -> PP[r] = OR tags[0..r]   (gives pre_i, cU, Mc)
//   - suffix OR-scan over [0,k0) -> S[r] = OR tags[r..k0-1]
//   - awT[i] = M & ~pre_i & ~S[i+1]; incremental update between k's:
//       awT[i] &= ~tag[k] (i<k), awT[k+1] = M & ~pre_{k+1}
//   - per k: flat 2x2-tiled pair sweep over i in [0,k], j in (k, N)
//   - last finished block (atomic counter) reduces partials -> out
// Every thread owns a fixed word lane myw = tid & 7 so M stays in one VGPR.
// ---------------------------------------------------------------------------
__global__ __launch_bounds__(256) void lambda_main(const u64* __restrict__ tags,
                                                   const u64* __restrict__ Mp,
                                                   const float* __restrict__ scores,
                                                   double* __restrict__ partials,
                                                   int* __restrict__ counter,
                                                   float* __restrict__ out) {
    __shared__ u64 T[W_ * LDP_];      // raw tags, transposed [w][r]
    __shared__ u64 BT[W_ * LDP_];     // b_j rows, transposed
    __shared__ u64 PA[W_ * LDP_];     // prefix scan ping
    __shared__ u64 PB[W_ * LDP_];     // prefix scan pong / suffix ping
    __shared__ u64 PC[W_ * LDP_];     // suffix pong / awT
    __shared__ u64 Msh[W_];
    __shared__ float scoresL[N_];
    __shared__ float redF[KC_][4];
    __shared__ double redD[4];
    __shared__ int isLast;

    const int kc  = blockIdx.x;
    const int b   = blockIdx.y;
    const int tid = threadIdx.x;
    const int k0  = kc * KC_;
    const int myw = tid & 7;          // fixed word lane (256 % 8 == 0)
    const int lane = tid & 63;
    const int wv   = tid >> 6;

    const u64 Mw = Mp[b * W_ + myw];
    if (tid < W_) Msh[tid] = Mw;      // tid<8 -> myw==tid
    for (int x = tid; x < N_; x += 256) scoresL[x] = scores[b * N_ + x];

    // single global pass: T, prefix-init, BT
    const u64* tg = tags + (long long)b * N_ * W_;
    for (int x = tid; x < N_ * W_; x += 256) {
        int r = x >> 3;               // word == myw
        u64 v = tg[x];
        T[myw * LDP_ + r]  = v;
        PA[myw * LDP_ + r] = v;
        if (r > k0) BT[myw * LDP_ + r] = Mw & ~v;
    }
    __syncthreads();

    // ---- prefix OR-scan over all N rows (8 steps, result ends in PA) ----
    u64* PP;
    {
        u64 *s = PA, *d = PB;
        for (int dd = 1; dd < N_; dd <<= 1) {
            for (int x = tid; x < N_ * W_; x += 256) {
                int r = x >> 3;
                u64 v = s[myw * LDP_ + r];
                if (r >= dd) v |= s[myw * LDP_ + r - dd];
                d[myw * LDP_ + r] = v;
            }
            __syncthreads();
            u64* t = s; s = d; d = t;
        }
        PP = s;                       // 8 swaps -> PA, but keep it general
    }
    u64* freeP = (PP == PA) ? PB : PA;

    // ---- suffix OR-scan over rows [0, k0) ----
    u64 *S = freeP, *D = PC;
    for (int x = tid; x < k0 * W_; x += 256)
        S[myw * LDP_ + (x >> 3)] = T[myw * LDP_ + (x >> 3)];
    __syncthreads();
    for (int dd = 1; dd < k0; dd <<= 1) {
        for (int x = tid; x < k0 * W_; x += 256) {
            int r = x >> 3;
            u64 v = S[myw * LDP_ + r];
            if (r + dd < k0) v |= S[myw * LDP_ + r + dd];
            D[myw * LDP_ + r] = v;
        }
        __syncthreads();
        u64* t = S; S = D; D = t;
    }
    u64* AWp = D;                     // the free plane

    // ---- build awT rows [0, k0] ----
    for (int x = tid; x < (k0 + 1) * W_; x += 256) {
        int i = x >> 3;
        u64 pre = (i == 1) ? 0ull
                : PP[myw * LDP_ + ((i == 0) ? (N_ - 2) : (i - 2))];
        u64 sv  = (i + 1 < k0) ? S[myw * LDP_ + i + 1] : 0ull;
        AWp[myw * LDP_ + i] = Mw & ~pre & ~sv;
    }
    __syncthreads();

    // ---- per-k sweeps ----
    float val[KC_] = {0.f, 0.f, 0.f, 0.f};
    for (int kk = 0; kk < KC_; ++kk) {
        const int k = k0 + kk;
        const int m = N_ - 1 - k;
        if (m > 0) {
            int cci = 0;
#pragma unroll
            for (int w = 0; w < W_; ++w)
                cci += __popcll(Msh[w] & ~PP[w * LDP_ + k]);
            const float cUk = (float)cci;

            const int nTj = (m + 1) >> 1;
            const int nTi = (k + 2) >> 1;          // ceil((k+1)/2)
            const int ntiles = nTi * nTj;
            const int dTi = 256 / nTj;
            const int rTj = 256 - dTi * nTj;
            int ti = tid / nTj;
            int tj = tid - ti * nTj;
            float aL = 0.f, aC = 0.f;
            for (int t = tid; t < ntiles; t += 256) {
                const int i0 = ti << 1;
                const int j0 = k + 1 + (tj << 1);
                const bool vi = (i0 + 1 <= k);
                const bool vj = (j0 + 1 < N_);
                const int i1 = vi ? i0 + 1 : i0;
                const int j1 = vj ? j0 + 1 : j0;
                int c00 = 0, c01 = 0, c10 = 0, c11 = 0;
#pragma unroll
                for (int w = 0; w < W_; ++w) {
                    u64 a0 = AWp[w * LDP_ + i0], a1 = AWp[w * LDP_ + i1];
                    u64 b0 = BT[w * LDP_ + j0],  b1 = BT[w * LDP_ + j1];
                    c00 += __popcll(a0 & b0); c01 += __popcll(a0 & b1);
                    c10 += __popcll(a1 & b0); c11 += __popcll(a1 & b1);
                }
                const float si0 = scoresL[i0], si1 = scoresL[i1];
                const float sj0 = scoresL[j0], sj1 = scoresL[j1];
                float l00 = 1.f / (1.f + __expf(si0 - sj0));
                float l01 = 1.f / (1.f + __expf(si0 - sj1)); if (!vj) l01 = 0.f;
                float l10 = 1.f / (1.f + __expf(si1 - sj0)); if (!vi) l10 = 0.f;
                float l11 = 1.f / (1.f + __expf(si1 - sj1)); if (!(vi && vj)) l11 = 0.f;
                aL += l00 + l01 + l10 + l11;
                aC += l00 * (float)c00 + l01 * (float)c01
                    + l10 * (float)c10 + l11 * (float)c11;
                ti += dTi; tj += rTj;
                if (tj >= nTj) { tj -= nTj; ++ti; }
            }
            val[kk] = cUk * aL - aC;
        }
        if (kk < KC_ - 1) {
            __syncthreads();
            // aw(k+1, i) = aw(k, i) & ~tag[k]  for i < k; row k unchanged
            const u64 tk = T[myw * LDP_ + k];
            for (int x = tid; x < k * W_; x += 256)
                AWp[myw * LDP_ + (x >> 3)] &= ~tk;
            // new row i = k+1: M & ~pre_{k+1}
            if (tid < W_) {
                const int i = k + 1;
                u64 pre = (i == 1) ? 0ull : PP[tid * LDP_ + i - 2];
                AWp[tid * LDP_ + i] = Msh[tid] & ~pre;
            }
            __syncthreads();
        }
    }

    // ---- reductions: 4 per-k block sums ----
#pragma unroll
    for (int kk = 0; kk < KC_; ++kk) {
        float v = val[kk];
        for (int off = 32; off >= 1; off >>= 1) v += __shfl_down(v, off, 64);
        if (lane == 0) redF[kk][wv] = v;
    }
    __syncthreads();
    if (tid < KC_) {
        const int k = k0 + tid;
        float s = redF[tid][0] + redF[tid][1] + redF[tid][2] + redF[tid][3];
        int mc = 1;
#pragma unroll
        for (int w = 0; w < W_; ++w) mc += __popcll(Msh[w]);
        partials[b * N_ + k] = (double)(s / log2f((float)(k + 2))) / (double)mc;
    }
    __syncthreads();
    if (tid == 0) {
        __threadfence();
        int done = atomicAdd(counter, 1);
        isLast = (done == NBLK_ * B_ - 1) ? 1 : 0;
    }
    __syncthreads();

    // ---- last block reduces all partials -> scalar out ----
    if (isLast) {
        __threadfence();
        double s = 0.0;
        for (int x = tid; x < B_ * N_; x += 256) s += partials[x];
        for (int off = 32; off >= 1; off >>= 1) s += __shfl_down(s, off, 64);
        if (lane == 0) redD[wv] = s;
        __syncthreads();
        if (tid == 0) {
            double t = redD[0] + redD[1] + redD[2] + redD[3];
            out[0] = (float)(t / ((double)(N_ + 1) * (double)B_));
        }
    }
}

// ---------------------------------------------------------------------------
extern "C" void kernel_launch(void* const* d_in, const int* in_sizes, int n_in,
                              void* d_out, int out_size, void* d_ws, size_t ws_size,
                              hipStream_t stream) {
    const float* y_scores = (const float*)d_in[0];   // B*N f32
    const float* Mf       = (const float*)d_in[1];   // B*T f32
    const float* emb      = (const float*)d_in[2];   // NUM_API*T f32
    const int*   preds    = (const int*)d_in[3];     // B*N i32
    float* out = (float*)d_out;

    // workspace layout (all 8-byte aligned)
    u64* tags = (u64*)d_ws;                               // B*N*W
    u64* Mp   = tags + (size_t)B_ * N_ * W_;              // B*W
    double* partials = (double*)(Mp + (size_t)B_ * W_);   // B*N
    int* counter = (int*)(partials + B_ * N_);            // 1 (+pad)

    // pack M inline via a tiny kernel-free trick is not possible; reuse
    // pack_tags-style packing for M by treating it as one extra row per batch:
    // cheaper: fold into pack_tags grid with 4 extra blocks.
    // Blocks [0, B_*N_) pack tag rows; blocks [B_*N_, B_*N_+B_) pack M.
    struct Launcher {
        static __global__ __launch_bounds__(64) void packM(const float* Mf,
                                                           u64* Mp) {
            int b = blockIdx.x, lane = threadIdx.x;
#pragma unroll
            for (int w = 0; w < W_; ++w) {
                float v = Mf[(long long)b * T_ + w * 64 + lane];
                u64 m = __ballot(v != 0.0f);
                if (lane == 0) Mp[b * W_ + w] = m;
            }
        }
    };

    pack_tags<<<B_ * N_, 64, 0, stream>>>(emb, preds, tags, counter);
    Launcher::packM<<<B_, 64, 0, stream>>>(Mf, Mp);
    dim3 grid(NBLK_, B_);
    lambda_main<<<grid, 256, 0, stream>>>(tags, Mp, y_scores,
                                          partials, counter, out);
}

// Round 8
// 119.673 us; speedup vs baseline: 1.1799x; 1.0253x over previous
//
#include <hip/hip_runtime.h>
#include <stdint.h>

typedef unsigned long long u64;

// Problem constants (from reference file)
constexpr int B_ = 4;
constexpr int N_ = 160;
constexpr int T_ = 512;
constexpr int W_ = T_ / 64;     // 8 u64 words per 512-bit row
constexpr int LDP_ = N_ + 1;    // padded LDS plane stride (u64 units)

// ---------------------------------------------------------------------------
// Kernel 1: pack tag rows (blocks 0..B*N-1) and M rows (blocks B*N..B*N+B-1).
// grid = B*N + B blocks, 64 threads. Block 0 zeroes the done-counter.
// ---------------------------------------------------------------------------
__global__ __launch_bounds__(64) void pack_all(const float* __restrict__ emb,
                                               const int* __restrict__ preds,
                                               const float* __restrict__ Mf,
                                               u64* __restrict__ tags,
                                               u64* __restrict__ Mp,
                                               int* __restrict__ counter) {
    const int row  = blockIdx.x;
    const int lane = threadIdx.x;
    if (row == 0 && lane == 0) *counter = 0;
    if (row < B_ * N_) {
        const float* src = emb + (long long)preds[row] * T_;
#pragma unroll
        for (int w = 0; w < W_; ++w) {
            u64 m = __ballot(src[w * 64 + lane] != 0.0f);
            if (lane == 0) tags[(long long)row * W_ + w] = m;
        }
    } else {
        const int b = row - B_ * N_;
#pragma unroll
        for (int w = 0; w < W_; ++w) {
            u64 m = __ballot(Mf[(long long)b * T_ + w * 64 + lane] != 0.0f);
            if (lane == 0) Mp[b * W_ + w] = m;
        }
    }
}

// ---------------------------------------------------------------------------
// Kernel 2: prefix-OR scan -> P, cU, Mc. grid = B blocks, 256 threads.
// ---------------------------------------------------------------------------
__global__ __launch_bounds__(256) void pack_scan(const u64* __restrict__ tags,
                                                 const u64* __restrict__ Mp,
                                                 u64* __restrict__ P,
                                                 float* __restrict__ cU,
                                                 float* __restrict__ Mc) {
    __shared__ u64 S0[N_ * W_];
    __shared__ u64 S1[N_ * W_];

    const int b   = blockIdx.x;
    const int tid = threadIdx.x;

    // M into registers (wave-uniform broadcast loads; no LDS race)
    u64 Mr[W_];
#pragma unroll
    for (int w = 0; w < W_; ++w) Mr[w] = Mp[b * W_ + w];

    for (int x = tid; x < N_ * W_; x += 256)
        S0[x] = tags[(long long)b * N_ * W_ + x];
    __syncthreads();

    u64* src = S0;
    u64* dst = S1;
    for (int d = 1; d < N_; d <<= 1) {
        for (int x = tid; x < N_ * W_; x += 256) {
            int r = x >> 3;           // W_ == 8
            u64 v = src[x];
            if (r >= d) v |= src[x - d * W_];
            dst[x] = v;
        }
        __syncthreads();
        u64* t = src; src = dst; dst = t;
    }
    // src[r*W_+w] = P[r] = OR tags[0..r]

    for (int x = tid; x < N_ * W_; x += 256)
        P[(long long)b * N_ * W_ + x] = src[x];

    if (tid < N_) {
        int c = 0;
#pragma unroll
        for (int w = 0; w < W_; ++w)
            c += __popcll(Mr[w] & ~src[tid * W_ + w]);
        cU[b * N_ + tid] = (float)c;
    }
    if (tid == 0) {
        int c = 0;
#pragma unroll
        for (int w = 0; w < W_; ++w) c += __popcll(Mr[w]);
        Mc[b] = (float)(c + 1);
    }
}

// ---------------------------------------------------------------------------
// Kernel 3: main + fused finalize. grid = (N, B) over k, 256 threads.
// Block (k,b):
//   suffix OR-scan over rows [0,k): S[r] = OR tags[r..k-1]  (trimmed steps)
//   awT[i] = M & ~pre_i & ~S[i+1]   (transposed LDS plane, LD = 161)
//   bT[j]  = M & ~tags[j]           (transposed)
//   2x2 register-tiled balanced pair sweep over i in [0,k], j in (k, N):
//     val = cU_k * sum(lam) - sum(lam * popcnt(aw_i & b_j))
//   last finished block (atomic counter + fences) reduces partials -> out.
// M is kept in per-thread registers Mr (broadcast loads) — NOT in LDS,
// because the bT build below runs before any barrier (R7 bug).
// ---------------------------------------------------------------------------
__global__ __launch_bounds__(256) void lambda_main(const u64* __restrict__ tags,
                                                   const u64* __restrict__ Mp,
                                                   const u64* __restrict__ P,
                                                   const float* __restrict__ cU,
                                                   const float* __restrict__ Mc,
                                                   const float* __restrict__ scores,
                                                   double* __restrict__ partials,
                                                   int* __restrict__ counter,
                                                   float* __restrict__ out) {
    __shared__ u64 S0[N_ * W_];       // suffix scan ping (row-major)
    __shared__ u64 S1[N_ * W_];       // suffix scan pong
    __shared__ u64 awT[W_ * LDP_];    // transposed [w][i]
    __shared__ u64 bT[W_ * LDP_];     // transposed [w][j]
    __shared__ float scoresL[N_];
    __shared__ float redF[4];
    __shared__ double redD[4];
    __shared__ int isLast;

    const int k   = blockIdx.x;
    const int b   = blockIdx.y;
    const int tid = threadIdx.x;
    const int m   = N_ - 1 - k;       // number of j values

    // M into registers (wave-uniform broadcast loads)
    u64 Mr[W_];
#pragma unroll
    for (int w = 0; w < W_; ++w) Mr[w] = Mp[b * W_ + w];

    for (int x = tid; x < N_; x += 256) scoresL[x] = scores[b * N_ + x];

    const u64* tg = tags + (long long)b * N_ * W_;
    // scan init: rows [0, k)
    for (int x = tid; x < k * W_; x += 256) S0[x] = tg[x];
    // bT rows (k, N)
    for (int x = tid; x < m * W_; x += 256) {
        int j = k + 1 + (x >> 3), w = x & 7;
        bT[w * LDP_ + j] = Mr[w] & ~tg[j * W_ + w];
    }
    __syncthreads();

    // ---- suffix OR-scan over rows [0,k): S[r] = OR tags[r..k-1] ----
    u64* src = S0;
    u64* dst = S1;
    for (int d = 1; d < k; d <<= 1) {
        for (int x = tid; x < k * W_; x += 256) {
            int r = x >> 3;
            u64 v = src[x];
            if (r + d < k) v |= src[x + d * W_];
            dst[x] = v;
        }
        __syncthreads();
        u64* t = src; src = dst; dst = t;
    }

    // ---- build awT rows [0, k] ----
    for (int x = tid; x < (k + 1) * W_; x += 256) {
        int i = x >> 3, w = x & 7;
        u64 pre;
        if (i == 1) pre = 0ull;
        else {
            int sr = (i == 0) ? (N_ - 2) : (i - 2);
            pre = P[((long long)b * N_ + sr) * W_ + w];
        }
        u64 sv = (i + 1 < k) ? src[(i + 1) * W_ + w] : 0ull;
        awT[w * LDP_ + i] = Mr[w] & ~pre & ~sv;
    }
    __syncthreads();

    // ---- 2x2 register-tiled balanced pair sweep ----
    float val = 0.0f;
    if (m > 0) {
        const float cUk = cU[b * N_ + k];
        const int nTj = (m + 1) >> 1;
        const int nTi = (k + 2) >> 1;          // ceil((k+1)/2)
        const int ntiles = nTi * nTj;
        const int dTi = 256 / nTj;
        const int rTj = 256 - dTi * nTj;
        int ti = tid / nTj;
        int tj = tid - ti * nTj;
        float aL = 0.f, aC = 0.f;
        for (int t = tid; t < ntiles; t += 256) {
            const int i0 = ti << 1;
            const int j0 = k + 1 + (tj << 1);
            const bool vi = (i0 + 1 <= k);
            const bool vj = (j0 + 1 < N_);
            const int i1 = vi ? i0 + 1 : i0;
            const int j1 = vj ? j0 + 1 : j0;
            int c00 = 0, c01 = 0, c10 = 0, c11 = 0;
#pragma unroll
            for (int w = 0; w < W_; ++w) {
                u64 a0 = awT[w * LDP_ + i0], a1 = awT[w * LDP_ + i1];
                u64 b0 = bT[w * LDP_ + j0],  b1 = bT[w * LDP_ + j1];
                c00 += __popcll(a0 & b0); c01 += __popcll(a0 & b1);
                c10 += __popcll(a1 & b0); c11 += __popcll(a1 & b1);
            }
            const float si0 = scoresL[i0], si1 = scoresL[i1];
            const float sj0 = scoresL[j0], sj1 = scoresL[j1];
            float l00 = 1.f / (1.f + __expf(si0 - sj0));
            float l01 = 1.f / (1.f + __expf(si0 - sj1)); if (!vj) l01 = 0.f;
            float l10 = 1.f / (1.f + __expf(si1 - sj0)); if (!vi) l10 = 0.f;
            float l11 = 1.f / (1.f + __expf(si1 - sj1)); if (!(vi && vj)) l11 = 0.f;
            aL += l00 + l01 + l10 + l11;
            aC += l00 * (float)c00 + l01 * (float)c01
                + l10 * (float)c10 + l11 * (float)c11;
            ti += dTi; tj += rTj;
            if (tj >= nTj) { tj -= nTj; ++ti; }
        }
        val = cUk * aL - aC;
    }

    // ---- block reduction + partial write ----
    for (int off = 32; off >= 1; off >>= 1) val += __shfl_down(val, off, 64);
    if ((tid & 63) == 0) redF[tid >> 6] = val;
    __syncthreads();
    if (tid == 0) {
        float s = redF[0] + redF[1] + redF[2] + redF[3];
        float invlog = 1.0f / log2f((float)(k + 2));
        partials[b * N_ + k] = (double)(s * invlog) / (double)Mc[b];
        __threadfence();
        int done = atomicAdd(counter, 1);
        isLast = (done == N_ * B_ - 1) ? 1 : 0;
    }
    __syncthreads();

    // ---- last block reduces all partials -> scalar out ----
    if (isLast) {
        __threadfence();
        double s = 0.0;
        for (int x = tid; x < B_ * N_; x += 256) s += partials[x];
        for (int off = 32; off >= 1; off >>= 1) s += __shfl_down(s, off, 64);
        if ((tid & 63) == 0) redD[tid >> 6] = s;
        __syncthreads();
        if (tid == 0) {
            double t = redD[0] + redD[1] + redD[2] + redD[3];
            out[0] = (float)(t / ((double)(N_ + 1) * (double)B_));
        }
    }
}

// ---------------------------------------------------------------------------
extern "C" void kernel_launch(void* const* d_in, const int* in_sizes, int n_in,
                              void* d_out, int out_size, void* d_ws, size_t ws_size,
                              hipStream_t stream) {
    const float* y_scores = (const float*)d_in[0];   // B*N f32
    const float* Mf       = (const float*)d_in[1];   // B*T f32
    const float* emb      = (const float*)d_in[2];   // NUM_API*T f32
    const int*   preds    = (const int*)d_in[3];     // B*N i32
    float* out = (float*)d_out;

    // workspace layout (all 8-byte aligned)
    u64* tags = (u64*)d_ws;                               // B*N*W
    u64* P    = tags + (size_t)B_ * N_ * W_;              // B*N*W
    u64* Mp   = P + (size_t)B_ * N_ * W_;                 // B*W
    double* partials = (double*)(Mp + B_ * W_);           // B*N
    float* cU = (float*)(partials + B_ * N_);             // B*N
    float* Mc = cU + B_ * N_;                             // B
    int* counter = (int*)(Mc + B_);                       // 1

    pack_all<<<B_ * N_ + B_, 64, 0, stream>>>(emb, preds, Mf, tags, Mp, counter);
    pack_scan<<<B_, 256, 0, stream>>>(tags, Mp, P, cU, Mc);
    dim3 grid(N_, B_);
    lambda_main<<<grid, 256, 0, stream>>>(tags, Mp, P, cU, Mc, y_scores,
                                          partials, counter, out);
}